// Round 4
// baseline (173.636 us; speedup 1.0000x reference)
//
#include <hip/hip_runtime.h>
#include <math.h>

#define LX 512
#define LY 128
#define BB 64
#define DD 512
#define NMSE (64*32*512)   // 1048576 elements
#define NGEMM 512          // GEMM blocks
#define NMSEB 64           // fused MSE blocks

typedef __attribute__((ext_vector_type(8)))  short v8s;   // 8 bf16 (4 VGPRs)
typedef __attribute__((ext_vector_type(16))) float v16f;  // 32x32 acc (16 f32)

// RNE float -> bf16 (bits in low 16)
__device__ inline unsigned bfrne(float x) {
    unsigned u = __float_as_uint(x);
    return (u + 0x7FFFu + ((u >> 16) & 1u)) >> 16;
}
__device__ inline float bfhi(unsigned h) { return __uint_as_float(h << 16); }

// ---------------- K_main: MFMA bf16x3 GEMM + norms + reductions + MSE --------
// Blocks [0,512): per-(b, x-tile) GEMM. 4 waves (2x2), C-tile 64x128, BK=64.
//   - raw values staged as bf16 hi/lo split (dot = hh + hl + lh, err ~1e-6)
//   - per-row/col sum-of-squares accumulated during staging (free norms)
//   - post-scale acc by invnx*invny, then fused hausdorff min/max reductions
// Blocks [512,576): MSE partial sums over predict/masked features.
__global__ __launch_bounds__(256) void k_main(const float* __restrict__ X,
                                              const float* __restrict__ Y,
                                              const float* __restrict__ P,
                                              const float* __restrict__ M,
                                              float* __restrict__ pm1,
                                              float* __restrict__ pcm,
                                              float* __restrict__ msep) {
    __shared__ unsigned short Ah[64 * 72], Al[64 * 72];    // [row][k] pad->72
    __shared__ unsigned short Bh[128 * 72], Bl[128 * 72];  // [col][k]
    __shared__ float sSqX[64], sSqY[128];  // ssq -> invnorm (in place)
    __shared__ float rowm[2][64];   // [wc][row]
    __shared__ float colm[2][128];  // [wr][col]
    __shared__ float sred[256];

    int tid = threadIdx.x;

    // ---------------- fused MSE path ----------------
    if (blockIdx.x >= NGEMM) {
        const float4* p4 = (const float4*)P;
        const float4* m4 = (const float4*)M;
        int n4 = NMSE / 4;
        float s = 0.0f;
        for (int i = (blockIdx.x - NGEMM) * 256 + tid; i < n4; i += NMSEB * 256) {
            float4 a = p4[i], b = m4[i];
            float dx = a.x - b.x, dy = a.y - b.y, dz = a.z - b.z, dw = a.w - b.w;
            s += dx*dx + dy*dy + dz*dz + dw*dw;
        }
        sred[tid] = s;
        __syncthreads();
        for (int o = 128; o > 0; o >>= 1) {
            if (tid < o) sred[tid] += sred[tid + o];
            __syncthreads();
        }
        if (tid == 0) msep[blockIdx.x - NGEMM] = sred[0];
        return;
    }

    // ---------------- GEMM path ----------------
    // XCD-aware swizzle: round-robin dispatch -> co-locate one b's 8 x-tiles
    // on one XCD so the Y-slice (256KB) stays L2-resident.
    int d  = blockIdx.x;
    int g  = d & 7;            // XCD (dispatch round-robin)
    int s_ = d >> 3;           // 0..63
    int b  = g * 8 + (s_ & 7); // 8 b's per XCD
    int xt = s_ >> 3;
    int x0 = xt * 64;

    int w    = tid >> 6;
    int wr   = w >> 1;         // row-wave: rows 32*wr .. +31
    int wc   = w & 1;          // col-wave: cols 64*wc .. +63
    int lane = tid & 63;
    int ln31 = lane & 31;
    int hi   = lane >> 5;
    int g8   = hi * 8;         // k sub-offset within fragment
    int arow = 32 * wr + ln31;
    int bc0  = 64 * wc + ln31;
    int bc1  = bc0 + 32;

    if (tid < 64) sSqX[tid] = 0.0f;
    else if (tid < 192) sSqY[tid - 64] = 0.0f;
    __syncthreads();

    v16f acc0, acc1;
    #pragma unroll
    for (int t = 0; t < 16; ++t) { acc0[t] = 0.0f; acc1[t] = 0.0f; }

    for (int k0 = 0; k0 < DD; k0 += 64) {
        // ---- stage A: 64 rows x 64 k = 1024 float4 ----
        #pragma unroll
        for (int i = 0; i < 4; ++i) {
            int f = tid + i * 256;
            int r = f >> 4, q = f & 15;
            float4 v = *(const float4*)&X[((size_t)(x0 + r) * BB + b) * DD + k0 + q * 4];
            float ss = v.x*v.x + v.y*v.y + v.z*v.z + v.w*v.w;
            #pragma unroll
            for (int o = 1; o < 16; o <<= 1) ss += __shfl_xor(ss, o, 64);
            if ((tid & 15) == 0) sSqX[r] += ss;   // unique writer per row
            unsigned h0 = bfrne(v.x), h1 = bfrne(v.y), h2 = bfrne(v.z), h3 = bfrne(v.w);
            float l0 = v.x - bfhi(h0), l1 = v.y - bfhi(h1),
                  l2 = v.z - bfhi(h2), l3 = v.w - bfhi(h3);
            uint2 hp, lp;
            hp.x = h0 | (h1 << 16);          hp.y = h2 | (h3 << 16);
            lp.x = bfrne(l0) | (bfrne(l1) << 16);
            lp.y = bfrne(l2) | (bfrne(l3) << 16);
            *(uint2*)&Ah[r * 72 + q * 4] = hp;
            *(uint2*)&Al[r * 72 + q * 4] = lp;
        }
        // ---- stage B: 128 cols x 64 k = 2048 float4 ----
        #pragma unroll
        for (int i = 0; i < 8; ++i) {
            int f = tid + i * 256;
            int r = f >> 4, q = f & 15;
            float4 v = *(const float4*)&Y[((size_t)r * BB + b) * DD + k0 + q * 4];
            float ss = v.x*v.x + v.y*v.y + v.z*v.z + v.w*v.w;
            #pragma unroll
            for (int o = 1; o < 16; o <<= 1) ss += __shfl_xor(ss, o, 64);
            if ((tid & 15) == 0) sSqY[r] += ss;
            unsigned h0 = bfrne(v.x), h1 = bfrne(v.y), h2 = bfrne(v.z), h3 = bfrne(v.w);
            float l0 = v.x - bfhi(h0), l1 = v.y - bfhi(h1),
                  l2 = v.z - bfhi(h2), l3 = v.w - bfhi(h3);
            uint2 hp, lp;
            hp.x = h0 | (h1 << 16);          hp.y = h2 | (h3 << 16);
            lp.x = bfrne(l0) | (bfrne(l1) << 16);
            lp.y = bfrne(l2) | (bfrne(l3) << 16);
            *(uint2*)&Bh[r * 72 + q * 4] = hp;
            *(uint2*)&Bl[r * 72 + q * 4] = lp;
        }
        __syncthreads();

        // ---- MFMA: 4 k-substeps of 16; hi*hi + hi*lo + lo*hi ----
        #pragma unroll
        for (int ks = 0; ks < 4; ++ks) {
            int koff = ks * 16 + g8;
            v8s ah  = *(const v8s*)&Ah[arow * 72 + koff];
            v8s al  = *(const v8s*)&Al[arow * 72 + koff];
            v8s bh0 = *(const v8s*)&Bh[bc0 * 72 + koff];
            v8s bl0 = *(const v8s*)&Bl[bc0 * 72 + koff];
            v8s bh1 = *(const v8s*)&Bh[bc1 * 72 + koff];
            v8s bl1 = *(const v8s*)&Bl[bc1 * 72 + koff];
            acc0 = __builtin_amdgcn_mfma_f32_32x32x16_bf16(ah, bh0, acc0, 0, 0, 0);
            acc1 = __builtin_amdgcn_mfma_f32_32x32x16_bf16(ah, bh1, acc1, 0, 0, 0);
            acc0 = __builtin_amdgcn_mfma_f32_32x32x16_bf16(ah, bl0, acc0, 0, 0, 0);
            acc1 = __builtin_amdgcn_mfma_f32_32x32x16_bf16(ah, bl1, acc1, 0, 0, 0);
            acc0 = __builtin_amdgcn_mfma_f32_32x32x16_bf16(al, bh0, acc0, 0, 0, 0);
            acc1 = __builtin_amdgcn_mfma_f32_32x32x16_bf16(al, bh1, acc1, 0, 0, 0);
        }
        __syncthreads();
    }

    // ---- ssq -> inverse norms (in place) ----
    if (tid < 64) sSqX[tid] = 1.0f / fmaxf(sqrtf(sSqX[tid]), 1e-12f);
    else if (tid < 192) sSqY[tid - 64] = 1.0f / fmaxf(sqrtf(sSqY[tid - 64]), 1e-12f);
    __syncthreads();

    // ---- post-scale: C/D layout (m74/m101): col=lane&31,
    //      row=(reg&3)+8*(reg>>2)+4*(lane>>5) ----
    float sy0 = sSqY[64 * wc + ln31];
    float sy1 = sSqY[64 * wc + 32 + ln31];
    #pragma unroll
    for (int t = 0; t < 16; ++t) {
        float sx = sSqX[32 * wr + (t & 3) + 8 * (t >> 2) + 4 * hi]; // broadcast read
        acc0[t] *= sx * sy0;
        acc1[t] *= sx * sy1;
    }

    // ---- row reduction: per-row max over this wave's 64 cols ----
    #pragma unroll
    for (int t = 0; t < 16; ++t) {
        float m = fmaxf(acc0[t], acc1[t]);
        #pragma unroll
        for (int o = 1; o < 32; o <<= 1) m = fmaxf(m, __shfl_xor(m, o, 64));
        if (ln31 == 0) {
            int rowid = (t & 3) + 8 * (t >> 2) + 4 * hi;
            rowm[wc][32 * wr + rowid] = m;
        }
    }

    // ---- col reduction: per-col max over this wave's 32 rows ----
    float c0 = acc0[0], c1 = acc1[0];
    #pragma unroll
    for (int t = 1; t < 16; ++t) { c0 = fmaxf(c0, acc0[t]); c1 = fmaxf(c1, acc1[t]); }
    c0 = fmaxf(c0, __shfl_xor(c0, 32, 64));
    c1 = fmaxf(c1, __shfl_xor(c1, 32, 64));
    if (lane < 32) {
        colm[wr][64 * wc + lane]      = c0;
        colm[wr][64 * wc + 32 + lane] = c1;
    }
    __syncthreads();

    if (tid < 64) {
        float v = fmaxf(rowm[0][tid], rowm[1][tid]);    // max over 128 cols
        #pragma unroll
        for (int o = 1; o < 64; o <<= 1) v = fminf(v, __shfl_xor(v, o, 64));
        if (tid == 0) pm1[b * 8 + xt] = v;              // min over 64 rows
    }
    if (tid >= 64 && tid < 192) {
        int c = tid - 64;
        pcm[(size_t)(b * 8 + xt) * 128 + c] = fmaxf(colm[0][c], colm[1][c]);
    }
}

// ---------------- K_final: epilogue (1 block) --------------------------------
__global__ __launch_bounds__(256) void k_final(const float* __restrict__ pm1,
                                               const float* __restrict__ pcm,
                                               const float* __restrict__ msep,
                                               const float* __restrict__ prob,
                                               const int* __restrict__ label,
                                               float* __restrict__ out) {
    int tid = threadIdx.x;
    __shared__ float sred[256];
    __shared__ float s_mse;

    sred[tid] = (tid < NMSEB) ? msep[tid] : 0.0f;
    __syncthreads();
    for (int o = 128; o > 0; o >>= 1) {
        if (tid < o) sred[tid] += sred[tid + o];
        __syncthreads();
    }
    if (tid == 0) s_mse = sred[0];
    __syncthreads();
    float mse_loss = s_mse / (float)NMSE;

    // 4 threads per batch; each handles a 32-col quarter with float4 loads
    int b = tid >> 2;
    int q = tid & 3;
    const float4* pcm4 = (const float4*)pcm;
    float m2p = 1e30f;
    #pragma unroll
    for (int j = 0; j < 8; ++j) {
        float4 cm = make_float4(-1e30f, -1e30f, -1e30f, -1e30f);
        #pragma unroll
        for (int t = 0; t < 8; ++t) {
            float4 v = pcm4[(b * 8 + t) * 32 + q * 8 + j];
            cm.x = fmaxf(cm.x, v.x); cm.y = fmaxf(cm.y, v.y);
            cm.z = fmaxf(cm.z, v.z); cm.w = fmaxf(cm.w, v.w);
        }
        m2p = fminf(m2p, fminf(fminf(cm.x, cm.y), fminf(cm.z, cm.w)));
    }
    #pragma unroll
    for (int o = 1; o < 4; o <<= 1) m2p = fminf(m2p, __shfl_xor(m2p, o, 64));

    float lossb = 0.0f;
    if (q == 0) {
        float m1 = 1e30f;
        #pragma unroll
        for (int t = 0; t < 8; ++t) m1 = fminf(m1, pm1[b * 8 + t]);
        float m = fminf(m1, m2p);
        float hd = sqrtf(fmaxf(2.0f - 2.0f * m, 0.0f));
        float lab = (float)label[b];
        float rel = fmaxf(0.5f - hd, 0.0f);
        float contrast = lab * hd * hd + (1.0f - lab) * rel * rel;
        float pv = prob[b];
        float logp   = fmaxf(logf(pv), -100.0f);
        float log1mp = fmaxf(log1pf(-pv), -100.0f);
        float bce = -(lab * logp + (1.0f - lab) * log1mp);
        lossb = contrast + bce;
    }
    __syncthreads();
    sred[tid] = lossb;
    __syncthreads();
    for (int o = 128; o > 0; o >>= 1) {
        if (tid < o) sred[tid] += sred[tid + o];
        __syncthreads();
    }
    if (tid == 0) out[0] = sred[0] / 64.0f + mse_loss;
}

// ---------------- launch -----------------------------------------------------
extern "C" void kernel_launch(void* const* d_in, const int* in_sizes, int n_in,
                              void* d_out, int out_size, void* d_ws, size_t ws_size,
                              hipStream_t stream) {
    const float* X = (const float*)d_in[0]; // encoded_frame [512,64,512]
    const float* Y = (const float*)d_in[1]; // encoded_word  [128,64,512]
    const float* P = (const float*)d_in[2]; // predict_mask_feature
    const float* M = (const float*)d_in[3]; // masked_feature
    const float* pv = (const float*)d_in[4];
    const int*   lb = (const int*)d_in[5];
    float* out = (float*)d_out;

    float* ws = (float*)d_ws;
    float* pm1  = ws;            // 512
    float* pcm  = ws + 512;      // 65536
    float* msep = ws + 66048;    // 64

    k_main<<<NGEMM + NMSEB, 256, 0, stream>>>(X, Y, P, M, pm1, pcm, msep);
    k_final<<<1, 256, 0, stream>>>(pm1, pcm, msep, pv, lb, out);
}

// Round 6
// 129.477 us; speedup vs baseline: 1.3411x; 1.3411x over previous
//
#include <hip/hip_runtime.h>
#include <hip/hip_bf16.h>
#include <math.h>

#define BB 64
#define DD 512
#define NMSE (64*32*512)   // 1048576 elements
#define NGEMM 512          // GEMM blocks
#define NMSEB 64           // fused MSE blocks
#define BK 64
#define PAD 72             // shorts/row: 144B stride, 16B-aligned, 0 conflicts (r4-proven)
#define KITERS (DD/BK)     // 8

typedef __attribute__((ext_vector_type(8)))  short v8s;   // 8 bf16 (4 VGPRs)
typedef __attribute__((ext_vector_type(16))) float v16f;  // 32x32 acc (16 f32)

__device__ inline unsigned short bfb(float f) {           // RNE f32->bf16 bits
    union { __hip_bfloat16 h; unsigned short s; } u;
    u.h = __float2bfloat16(f);
    return u.s;
}
__device__ inline float bff(unsigned short s) { return __uint_as_float(((unsigned)s) << 16); }

// convert float4 -> hi/lo bf16, store to LDS, accumulate sum-of-squares in reg
__device__ inline void cvt_store(float4 v, unsigned short* __restrict__ H,
                                 unsigned short* __restrict__ L, int off, float& ssq) {
    ssq = fmaf(v.x, v.x, ssq); ssq = fmaf(v.y, v.y, ssq);
    ssq = fmaf(v.z, v.z, ssq); ssq = fmaf(v.w, v.w, ssq);
    unsigned short h0 = bfb(v.x), h1 = bfb(v.y), h2 = bfb(v.z), h3 = bfb(v.w);
    float l0 = v.x - bff(h0), l1 = v.y - bff(h1), l2 = v.z - bff(h2), l3 = v.w - bff(h3);
    uint2 hp, lp;
    hp.x = (unsigned)h0 | ((unsigned)h1 << 16);
    hp.y = (unsigned)h2 | ((unsigned)h3 << 16);
    lp.x = (unsigned)bfb(l0) | ((unsigned)bfb(l1) << 16);
    lp.y = (unsigned)bfb(l2) | ((unsigned)bfb(l3) << 16);
    *(uint2*)&H[off] = hp;
    *(uint2*)&L[off] = lp;
}

// barrier that waits ONLY lgkmcnt (LDS) — prefetch global loads stay in flight
// across it (vmcnt un-drained; compiler emits the vmcnt wait at first reg use).
__device__ inline void bar_lds() {
    asm volatile("s_waitcnt lgkmcnt(0)" ::: "memory");
    __builtin_amdgcn_s_barrier();
    asm volatile("" ::: "memory");
}

// ---------------- K_main: MFMA bf16x3 GEMM + reg-ssq + reductions + MSE ------
// Blocks [0,512): per-(b,xt) GEMM. 8 waves (2x4), C-tile 64x128, BK=64.
//   Each wave: one 32x32 MFMA sub-tile (1 v16f acc).
//   Register prefetch of next k-tile rides across the MFMA phase (T14).
// Blocks [512,576): MSE partial sums.
__global__ __launch_bounds__(512, 4) void k_main(const float* __restrict__ X,
                                                 const float* __restrict__ Y,
                                                 const float* __restrict__ P,
                                                 const float* __restrict__ M,
                                                 float* __restrict__ pm1,
                                                 float* __restrict__ pcm,
                                                 float* __restrict__ msep) {
    __shared__ unsigned short Ah[64 * PAD], Al[64 * PAD];    // [row][k]
    __shared__ unsigned short Bh[128 * PAD], Bl[128 * PAD];  // [col][k]
    __shared__ float sSqX[64], sSqY[128];
    __shared__ float rowm[4][64];   // [wc][row]
    __shared__ float colm[2][128];  // [wr][col]
    __shared__ float sred[512];

    int tid = threadIdx.x;

    // ---------------- fused MSE path ----------------
    if (blockIdx.x >= NGEMM) {
        const float4* p4 = (const float4*)P;
        const float4* m4 = (const float4*)M;
        int n4 = NMSE / 4;
        float s = 0.0f;
        for (int i = (blockIdx.x - NGEMM) * 512 + tid; i < n4; i += NMSEB * 512) {
            float4 a = p4[i], b = m4[i];
            float dx = a.x - b.x, dy = a.y - b.y, dz = a.z - b.z, dw = a.w - b.w;
            s += dx*dx + dy*dy + dz*dz + dw*dw;
        }
        sred[tid] = s;
        __syncthreads();
        for (int o = 256; o > 0; o >>= 1) {
            if (tid < o) sred[tid] += sred[tid + o];
            __syncthreads();
        }
        if (tid == 0) msep[blockIdx.x - NGEMM] = sred[0];
        return;
    }

    // ---------------- GEMM path ----------------
    // XCD-aware swizzle: co-locate one b's x-tiles per XCD (Y slice L2-hot)
    int d  = blockIdx.x;
    int g  = d & 7;
    int s_ = d >> 3;
    int b  = g * 8 + (s_ & 7);
    int xt = s_ >> 3;
    int x0 = xt * 64;

    int w    = tid >> 6;       // 8 waves
    int wr   = w >> 2;         // 0..1: rows 32*wr..+31
    int wc   = w & 3;          // 0..3: cols 32*wc..+31
    int lane = tid & 63;
    int ln31 = lane & 31;
    int hi   = lane >> 5;
    int g8   = hi * 8;
    int arow = 32 * wr + ln31;
    int bcol = 32 * wc + ln31;

    // staging map: 512 threads; row r gets 16 threads (q = float4 index in BK=64)
    int r  = tid >> 4;          // 0..31
    int q  = tid & 15;          // 0..15
    const float* gA0 = &X[((size_t)(x0 + r) * BB + b) * DD + q * 4];
    const float* gA1 = &X[((size_t)(x0 + r + 32) * BB + b) * DD + q * 4];
    const float* gB0 = &Y[((size_t)(r)      * BB + b) * DD + q * 4];
    const float* gB1 = &Y[((size_t)(r + 32) * BB + b) * DD + q * 4];
    const float* gB2 = &Y[((size_t)(r + 64) * BB + b) * DD + q * 4];
    const float* gB3 = &Y[((size_t)(r + 96) * BB + b) * DD + q * 4];

    v16f acc;
    #pragma unroll
    for (int t = 0; t < 16; ++t) acc[t] = 0.0f;
    float sqA0 = 0.0f, sqA1 = 0.0f, sqB0 = 0.0f, sqB1 = 0.0f, sqB2 = 0.0f, sqB3 = 0.0f;

    // prefetch tile 0
    float4 pa0 = *(const float4*)(gA0);
    float4 pa1 = *(const float4*)(gA1);
    float4 pb0 = *(const float4*)(gB0);
    float4 pb1 = *(const float4*)(gB1);
    float4 pb2 = *(const float4*)(gB2);
    float4 pb3 = *(const float4*)(gB3);

    for (int it = 0; it < KITERS; ++it) {
        // convert + LDS-write current tile from regs (waits vmcnt here, auto)
        cvt_store(pa0, Ah, Al, (r)      * PAD + q * 4, sqA0);
        cvt_store(pa1, Ah, Al, (r + 32) * PAD + q * 4, sqA1);
        cvt_store(pb0, Bh, Bl, (r)      * PAD + q * 4, sqB0);
        cvt_store(pb1, Bh, Bl, (r + 32) * PAD + q * 4, sqB1);
        cvt_store(pb2, Bh, Bl, (r + 64) * PAD + q * 4, sqB2);
        cvt_store(pb3, Bh, Bl, (r + 96) * PAD + q * 4, sqB3);
        bar_lds();   // tile visible; vmcnt NOT drained

        // issue next tile's loads — in flight across the MFMA phase
        if (it < KITERS - 1) {
            int k0 = (it + 1) * BK;
            pa0 = *(const float4*)(gA0 + k0);
            pa1 = *(const float4*)(gA1 + k0);
            pb0 = *(const float4*)(gB0 + k0);
            pb1 = *(const float4*)(gB1 + k0);
            pb2 = *(const float4*)(gB2 + k0);
            pb3 = *(const float4*)(gB3 + k0);
        }

        // MFMA: 4 k-substeps of 16; hi*hi + hi*lo + lo*hi
        #pragma unroll
        for (int ks = 0; ks < 4; ++ks) {
            int koff = ks * 16 + g8;
            v8s ah = *(const v8s*)&Ah[arow * PAD + koff];
            v8s al = *(const v8s*)&Al[arow * PAD + koff];
            v8s bh = *(const v8s*)&Bh[bcol * PAD + koff];
            v8s bl = *(const v8s*)&Bl[bcol * PAD + koff];
            acc = __builtin_amdgcn_mfma_f32_32x32x16_bf16(ah, bh, acc, 0, 0, 0);
            acc = __builtin_amdgcn_mfma_f32_32x32x16_bf16(ah, bl, acc, 0, 0, 0);
            acc = __builtin_amdgcn_mfma_f32_32x32x16_bf16(al, bh, acc, 0, 0, 0);
        }
        bar_lds();   // frag reads done before next overwrite
    }

    // ---- ssq reduction: 16 threads share a row ----
    #pragma unroll
    for (int o = 1; o < 16; o <<= 1) {
        sqA0 += __shfl_xor(sqA0, o, 64);
        sqA1 += __shfl_xor(sqA1, o, 64);
        sqB0 += __shfl_xor(sqB0, o, 64);
        sqB1 += __shfl_xor(sqB1, o, 64);
        sqB2 += __shfl_xor(sqB2, o, 64);
        sqB3 += __shfl_xor(sqB3, o, 64);
    }
    if (q == 0) {
        sSqX[r]      = sqA0;  sSqX[r + 32] = sqA1;
        sSqY[r]      = sqB0;  sSqY[r + 32] = sqB1;
        sSqY[r + 64] = sqB2;  sSqY[r + 96] = sqB3;
    }
    __syncthreads();
    if (tid < 64) sSqX[tid] = 1.0f / fmaxf(sqrtf(sSqX[tid]), 1e-12f);
    else if (tid < 192) sSqY[tid - 64] = 1.0f / fmaxf(sqrtf(sSqY[tid - 64]), 1e-12f);
    __syncthreads();

    // ---- post-scale: C/D layout (m74/m101): col=lane&31,
    //      row=(t&3)+8*(t>>2)+4*(lane>>5) ----
    float sy = sSqY[32 * wc + ln31];
    #pragma unroll
    for (int t = 0; t < 16; ++t) {
        float sx = sSqX[32 * wr + (t & 3) + 8 * (t >> 2) + 4 * hi];
        acc[t] *= sx * sy;
    }

    // ---- row reduction: per-row max over this wave's 32 cols ----
    #pragma unroll
    for (int t = 0; t < 16; ++t) {
        float m = acc[t];
        #pragma unroll
        for (int o = 1; o < 32; o <<= 1) m = fmaxf(m, __shfl_xor(m, o, 64));
        if (ln31 == 0) {
            int rowid = (t & 3) + 8 * (t >> 2) + 4 * hi;
            rowm[wc][32 * wr + rowid] = m;
        }
    }

    // ---- col reduction: per-col max over this wave's 32 rows ----
    float cm = acc[0];
    #pragma unroll
    for (int t = 1; t < 16; ++t) cm = fmaxf(cm, acc[t]);
    cm = fmaxf(cm, __shfl_xor(cm, 32, 64));
    if (lane < 32) colm[wr][32 * wc + lane] = cm;
    __syncthreads();

    if (tid < 64) {
        float v = fmaxf(fmaxf(rowm[0][tid], rowm[1][tid]),
                        fmaxf(rowm[2][tid], rowm[3][tid]));   // max over 128 cols
        #pragma unroll
        for (int o = 1; o < 64; o <<= 1) v = fminf(v, __shfl_xor(v, o, 64));
        if (tid == 0) pm1[b * 8 + xt] = v;                    // min over 64 rows
    }
    if (tid >= 64 && tid < 192) {
        int c = tid - 64;
        pcm[(size_t)(b * 8 + xt) * 128 + c] = fmaxf(colm[0][c], colm[1][c]);
    }
}

// ---------------- K_red: per-batch hausdorff + loss (64 blocks) --------------
__global__ __launch_bounds__(256) void k_red(const float* __restrict__ pm1,
                                             const float* __restrict__ pcm,
                                             const float* __restrict__ prob,
                                             const int* __restrict__ label,
                                             float* __restrict__ lossb) {
    __shared__ float red[128];
    int tid = threadIdx.x;
    int b = blockIdx.x;

    if (tid < 128) {
        float cm = -1e30f;
        #pragma unroll
        for (int t = 0; t < 8; ++t)
            cm = fmaxf(cm, pcm[(size_t)(b * 8 + t) * 128 + tid]);
        red[tid] = cm;   // per-col max over all 512 rows
    }
    __syncthreads();
    if (tid < 64) {
        float v = fminf(red[tid], red[tid + 64]);
        #pragma unroll
        for (int o = 1; o < 64; o <<= 1) v = fminf(v, __shfl_xor(v, o, 64));  // m2
        if (tid == 0) {
            float m1 = 1e30f;
            #pragma unroll
            for (int t = 0; t < 8; ++t) m1 = fminf(m1, pm1[b * 8 + t]);
            float m = fminf(m1, v);
            float hd = sqrtf(fmaxf(2.0f - 2.0f * m, 0.0f));
            float lab = (float)label[b];
            float rel = fmaxf(0.5f - hd, 0.0f);
            float contrast = lab * hd * hd + (1.0f - lab) * rel * rel;
            float pv = prob[b];
            float logp   = fmaxf(logf(pv), -100.0f);
            float log1mp = fmaxf(log1pf(-pv), -100.0f);
            float bce = -(lab * logp + (1.0f - lab) * log1mp);
            lossb[b] = contrast + bce;
        }
    }
}

// ---------------- K_fin: final combine (1 block) -----------------------------
__global__ __launch_bounds__(64) void k_fin(const float* __restrict__ lossb,
                                            const float* __restrict__ msep,
                                            float* __restrict__ out) {
    int tid = threadIdx.x;
    float v = lossb[tid] * (1.0f / 64.0f) + msep[tid] * (1.0f / (float)NMSE);
    #pragma unroll
    for (int o = 32; o > 0; o >>= 1) v += __shfl_down(v, o, 64);
    if (tid == 0) out[0] = v;
}

// ---------------- launch -----------------------------------------------------
extern "C" void kernel_launch(void* const* d_in, const int* in_sizes, int n_in,
                              void* d_out, int out_size, void* d_ws, size_t ws_size,
                              hipStream_t stream) {
    const float* X = (const float*)d_in[0]; // encoded_frame [512,64,512]
    const float* Y = (const float*)d_in[1]; // encoded_word  [128,64,512]
    const float* P = (const float*)d_in[2]; // predict_mask_feature
    const float* M = (const float*)d_in[3]; // masked_feature
    const float* pv = (const float*)d_in[4];
    const int*   lb = (const int*)d_in[5];
    float* out = (float*)d_out;

    float* ws = (float*)d_ws;
    float* pm1   = ws;            // 512
    float* pcm   = ws + 512;      // 65536
    float* msep  = ws + 66048;    // 64
    float* lossb = ws + 66112;    // 64

    k_main<<<NGEMM + NMSEB, 512, 0, stream>>>(X, Y, P, M, pm1, pcm, msep);
    k_red<<<BB, 256, 0, stream>>>(pm1, pcm, pv, lb, lossb);
    k_fin<<<1, 64, 0, stream>>>(lossb, msep, out);
}